// Round 18
// baseline (1635.000 us; speedup 1.0000x reference)
//
#include <hip/hip_runtime.h>

// BiLSTM B=512 T=1024 D=64 H=50, 2 layers bidir, FC on h[:,-1].
//  Phase A (per T-chunk): xp_gemm l0 (MFMA split-bf16, both dirs) -> lstm_scan l0
//  Phase B (per T-chunk): xp_gemm l1f -> lstm_scan l1f (final h only)
//  Phase C: l1 backward single step at t=T-1 (h0=c0=0 -> no Whh), Phase D: FC.
//
// Scan (round 18): round-17 base (k-packed pk_fma, asm px ring) + LDS h
// broadcast. r17's 50 readlane + ~50 v_mov (SGPR->VGPR pair assembly for
// pk_fma's 64-bit operands) ~= 200 issue-cyc/step. Replacement: h -> LDS
// (1 ds_write), read 25 aligned f32x2 pairs back (<=13 ds_read_b128,
// same-address broadcast, conflict-free). Single wave per block -> DS ops
// are in-order, no barrier; pairs arrive pre-aligned for pk_fma.

#define BATCH 512
#define TT    1024
#define HH    50
#define GG    200

typedef __attribute__((ext_vector_type(2))) float  f32x2;
typedef __attribute__((ext_vector_type(4))) float  f32x4;
typedef __attribute__((ext_vector_type(8))) short  bf16x8;

__device__ __forceinline__ float sigf(float x)     { return 1.f / (1.f + __expf(-x)); }
__device__ __forceinline__ float tanhfast(float x) { return 1.f - 2.f / (__expf(2.f * x) + 1.f); }

__device__ __forceinline__ void split8(const float (&v)[8], bf16x8& hi, bf16x8& lo) {
#pragma unroll
  for (int j = 0; j < 8; ++j) {
    unsigned b = __float_as_uint(v[j]);
    hi[j] = (short)(b >> 16);
    float rem = v[j] - __uint_as_float(b & 0xFFFF0000u);
    lo[j] = (short)(__float_as_uint(rem) >> 16);
  }
}

// B-frag: B[k][col], k = ks*32 + 8*(lane>>4) + j, col = n*16 + (lane&15)
__device__ __forceinline__ void load_wfrag(const float* __restrict__ W, int ld, int kvalid,
                                           int n, int ks, int lane, bf16x8& hi, bf16x8& lo) {
  const int col = n * 16 + (lane & 15);
  const int kb  = ks * 32 + ((lane >> 4) << 3);
  float v[8];
#pragma unroll
  for (int j = 0; j < 8; ++j) {
    const int k = kb + j;
    v[j] = (col < GG && k < kvalid) ? W[col * ld + k] : 0.f;
  }
  split8(v, hi, lo);
}

// ================= xp GEMM: XP[dir][b][s][200] = X[row(b,s)] @ W^T + bih + bhh =================
template<int DINK, int KS, bool SPLITN>
__global__ __launch_bounds__(256, 1) void xp_gemm(
    const float* __restrict__ X,
    const float* __restrict__ Wf, const float* __restrict__ bihf, const float* __restrict__ bhhf,
    const float* __restrict__ Wb, const float* __restrict__ bihb, const float* __restrict__ bhhb,
    float* __restrict__ XP, int t0, int CH)
{
  const int lane = threadIdx.x & 63;
  const int wid  = threadIdx.x >> 6;
  const int dir  = blockIdx.y;
  const float* W   = dir ? Wb : Wf;
  const float* bih = dir ? bihb : bihf;
  const float* bhh = dir ? bhhb : bhhf;

  constexpr int MAXT = SPLITN ? 7 : 13;
  const int tb = SPLITN ? ((wid & 1) * 7) : 0;
  const int tn = SPLITN ? ((wid & 1) ? 6 : 7) : 13;

  bf16x8 whi[MAXT][KS], wlo[MAXT][KS];
  float bias[MAXT];
#pragma unroll
  for (int i = 0; i < MAXT; ++i) {
    if (i < tn) {
      const int n = tb + i;
#pragma unroll
      for (int ks = 0; ks < KS; ++ks)
        load_wfrag(W, DINK, DINK, n, ks, lane, whi[i][ks], wlo[i][ks]);
      const int col = n * 16 + (lane & 15);
      bias[i] = (col < GG) ? (bih[col] + bhh[col]) : 0.f;
    }
  }

  const int rw      = SPLITN ? ((int)blockIdx.x * 2 + (wid >> 1)) : ((int)blockIdx.x * 4 + wid);
  const int stride  = SPLITN ? ((int)gridDim.x * 2) : ((int)gridDim.x * 4);
  const int gpb     = CH >> 4;
  const int ngroups = BATCH * gpb;
  const int m = lane & 15;

  auto loadA = [&](int g, float (&v)[KS][8]) {
    const int b    = g / gpb;
    const int toff = (g - b * gpb) << 4;
    const int s    = toff + m;
    const int tg   = dir ? (TT - 1 - (t0 + s)) : (t0 + s);
    const float* base = X + ((size_t)b * TT + tg) * DINK;
#pragma unroll
    for (int ks = 0; ks < KS; ++ks) {
      const int kb = ks * 32 + ((lane >> 4) << 3);
      if (kb + 8 <= DINK) {
        f32x4 a = *(const f32x4*)(base + kb);
        f32x4 bq = *(const f32x4*)(base + kb + 4);
#pragma unroll
        for (int q = 0; q < 4; ++q) { v[ks][q] = a[q]; v[ks][4 + q] = bq[q]; }
      } else if (kb < DINK) {
        f32x4 a = *(const f32x4*)(base + kb);
#pragma unroll
        for (int q = 0; q < 4; ++q) { v[ks][q] = a[q]; v[ks][4 + q] = 0.f; }
      } else {
#pragma unroll
        for (int q = 0; q < 8; ++q) v[ks][q] = 0.f;
      }
    }
  };

  float vc[KS][8], vn[KS][8];
  if (rw < ngroups) loadA(rw, vc);
  for (int g = rw; g < ngroups; g += stride) {
    if (g + stride < ngroups) loadA(g + stride, vn);
    bf16x8 ah[KS], al[KS];
#pragma unroll
    for (int ks = 0; ks < KS; ++ks) split8(vc[ks], ah[ks], al[ks]);
    const int b    = g / gpb;
    const int toff = (g - b * gpb) << 4;
    float* out = XP + (((size_t)dir * BATCH + b) * CH + toff) * GG;
#pragma unroll
    for (int i = 0; i < MAXT; ++i) {
      if (i < tn) {
        f32x4 acc = {0.f, 0.f, 0.f, 0.f};
#pragma unroll
        for (int ks = 0; ks < KS; ++ks) {
          acc = __builtin_amdgcn_mfma_f32_16x16x32_bf16(ah[ks], whi[i][ks], acc, 0, 0, 0);
          acc = __builtin_amdgcn_mfma_f32_16x16x32_bf16(al[ks], whi[i][ks], acc, 0, 0, 0);
          acc = __builtin_amdgcn_mfma_f32_16x16x32_bf16(ah[ks], wlo[i][ks], acc, 0, 0, 0);
        }
        const int col = (tb + i) * 16 + (lane & 15);
        if (col < GG) {
          const int rb = (lane >> 4) * 4;
#pragma unroll
          for (int q = 0; q < 4; ++q) out[(size_t)(rb + q) * GG + col] = acc[q] + bias[i];
        }
      }
    }
#pragma unroll
    for (int ks = 0; ks < KS; ++ks)
#pragma unroll
      for (int q = 0; q < 8; ++q) vc[ks][q] = vn[ks][q];
  }
}

// ================= scan: one WAVE per (dir,seq); LDS h-broadcast ===========
template<bool L0>
__global__ __attribute__((amdgpu_flat_work_group_size(64, 64), amdgpu_waves_per_eu(1, 1)))
void lstm_scan(
    const float* __restrict__ XP,     // [dir][b][s][200], bias included
    const float* __restrict__ Whh_f, const float* __restrict__ Whh_b,
    float* __restrict__ hseq,         // L0: [b][t][100]
    float* __restrict__ hlast,        // !L0: [b][100] cols 0..49
    float* __restrict__ stC, float* __restrict__ stH,
    int t0, int CH)
{
  const int lane = threadIdx.x;                  // 0..63
  const int unit = blockIdx.x;                   // (dir*512+b) for L0, b for L1
  const int dir  = L0 ? (unit >> 9) : 0;
  const int b    = L0 ? (unit & 511) : unit;
  const bool act = lane < HH;
  const int  jw  = act ? lane : 0;               // clamped: safe loads for dead lanes
  const float* Whh = (L0 && dir) ? Whh_b : Whh_f;

  __shared__ __align__(16) float hsm[64];        // h broadcast buffer (one wave: in-order DS)
  const f32x2* hsm2 = (const f32x2*)hsm;

  // ---- weights as k-pairs: wI2,wF2 -> VGPR; wG2,wO2 -> AGPR ----
  f32x2 wI2[25], wF2[25], wG2[25], wO2[25];
#pragma unroll
  for (int m = 0; m < 25; ++m) {
    wI2[m].x = Whh[(size_t)jw * HH + 2 * m];
    wI2[m].y = Whh[(size_t)jw * HH + 2 * m + 1];
    wF2[m].x = Whh[(size_t)(HH + jw) * HH + 2 * m];
    wF2[m].y = Whh[(size_t)(HH + jw) * HH + 2 * m + 1];
    wG2[m].x = Whh[(size_t)(2 * HH + jw) * HH + 2 * m];
    wG2[m].y = Whh[(size_t)(2 * HH + jw) * HH + 2 * m + 1];
    wO2[m].x = Whh[(size_t)(3 * HH + jw) * HH + 2 * m];
    wO2[m].y = Whh[(size_t)(3 * HH + jw) * HH + 2 * m + 1];
  }
#pragma unroll
  for (int m = 0; m < 25; ++m) {
    asm volatile("" : "+v"(wI2[m]), "+v"(wF2[m]), "+a"(wG2[m]), "+a"(wO2[m]));
  }

  float c = 0.f, h = 0.f;
  if (t0 > 0 && act) { c = stC[unit * 64 + lane]; h = stH[unit * 64 + lane]; }
  hsm[lane] = act ? h : 0.f;                     // seed broadcast buffer

  const float* xp = XP + (size_t)unit * CH * GG + jw;   // lane-adjusted base

  // ---- depth-4 asm load ring (round 11, verified) ----
  float px[4][4];
#pragma unroll
  for (int d = 0; d < 4; ++d) {
    const float* pa = xp + (size_t)d * GG;
    asm volatile("global_load_dword %0, %1, off"             : "=v"(px[d][0]) : "v"(pa));
    asm volatile("global_load_dword %0, %1, off offset:200"  : "=v"(px[d][1]) : "v"(pa));
    asm volatile("global_load_dword %0, %1, off offset:400"  : "=v"(px[d][2]) : "v"(pa));
    asm volatile("global_load_dword %0, %1, off offset:600"  : "=v"(px[d][3]) : "v"(pa));
  }

  for (int s0 = 0; s0 < CH; s0 += 4) {
#pragma unroll
    for (int d = 0; d < 4; ++d) {
      const int s = s0 + d;

      // ---- LDS broadcast read: 25 aligned f32x2 pairs (compiler merges to b128) ----
      f32x2 hp[25];
#pragma unroll
      for (int m = 0; m < 25; ++m) hp[m] = hsm2[m];

      asm volatile("s_waitcnt vmcnt(12)"); // px(s) ready (12 newer loads in flight)
      __builtin_amdgcn_sched_barrier(0);   // rule #18: nothing crosses the wait

      f32x2 aI2, aF2, aG2, aO2;
      aI2.x = px[d][0]; aI2.y = 0.f;
      aF2.x = px[d][1]; aF2.y = 0.f;
      aG2.x = px[d][2]; aG2.y = 0.f;
      aO2.x = px[d][3]; aO2.y = 0.f;
#pragma unroll
      for (int m = 0; m < 25; ++m) {
        aI2 = hp[m] * wI2[m] + aI2;     // contraction -> v_pk_fma_f32
        aF2 = hp[m] * wF2[m] + aF2;
        aG2 = hp[m] * wG2[m] + aG2;
        aO2 = hp[m] * wO2[m] + aO2;
      }
      const float aI = aI2.x + aI2.y;
      const float aF = aF2.x + aF2.y;
      const float aG = aG2.x + aG2.y;
      const float aO = aO2.x + aO2.y;

      // refill slot d for step s+4 (after consumption; WAR on px[d] in-order)
      {
        int sp = s + 4; if (sp > CH - 1) sp = CH - 1;
        const float* pa = xp + (size_t)sp * GG;
        asm volatile("global_load_dword %0, %1, off"             : "=v"(px[d][0]) : "v"(pa));
        asm volatile("global_load_dword %0, %1, off offset:200"  : "=v"(px[d][1]) : "v"(pa));
        asm volatile("global_load_dword %0, %1, off offset:400"  : "=v"(px[d][2]) : "v"(pa));
        asm volatile("global_load_dword %0, %1, off offset:600"  : "=v"(px[d][3]) : "v"(pa));
      }

      const float iv = sigf(aI), fv = sigf(aF), gv = tanhfast(aG), ov = sigf(aO);
      c = fv * c + iv * gv;
      h = ov * tanhfast(c);
      hsm[lane] = act ? h : 0.f;       // broadcast for next step (in-order DS, one wave)
      if (act) {
        if (L0) {
          const int tg = dir ? (TT - 1 - (t0 + s)) : (t0 + s);
          hseq[((size_t)b * TT + tg) * 100 + dir * HH + lane] = h;
        } else if (t0 + s == TT - 1) {
          hlast[b * 100 + lane] = h;
        }
      }
    }
  }
  if (act) { stC[unit * 64 + lane] = c; stH[unit * 64 + lane] = h; }
}

// ------------- Layer 1 backward at t=T-1: single step, h0=c0=0 -> no Whh term. ----
__global__ __launch_bounds__(256) void l1b_step(
    const float* __restrict__ hl0, const float* __restrict__ Wih,
    const float* __restrict__ bih, const float* __restrict__ bhh,
    float* __restrict__ h1cat)
{
    const int row = blockIdx.x;
    const int tid = threadIdx.x;
    __shared__ float in_s[100];
    __shared__ float gbuf[4 * HH];

    const float* inp = hl0 + ((size_t)row * TT + (TT - 1)) * 100;
    if (tid < 100) in_s[tid] = inp[tid];
    __syncthreads();
    if (tid < 4 * HH) {
        float acc = bih[tid] + bhh[tid];
#pragma unroll
        for (int k = 0; k < 100; ++k) acc += in_s[k] * Wih[tid * 100 + k];
        gbuf[tid] = acc;
    }
    __syncthreads();
    if (tid < HH) {
        float iv = sigf(gbuf[tid]);
        float gv = tanhfast(gbuf[2 * HH + tid]);
        float ov = sigf(gbuf[3 * HH + tid]);
        float cc = iv * gv;
        h1cat[row * 100 + HH + tid] = ov * tanhfast(cc);
    }
}

__global__ void fc_out(const float* __restrict__ h1cat,
                       const float* __restrict__ fcw, const float* __restrict__ fcb,
                       float* __restrict__ out)
{
    const int b = blockIdx.x * blockDim.x + threadIdx.x;
    if (b < BATCH) {
        float acc = fcb[0];
#pragma unroll 4
        for (int k = 0; k < 100; ++k) acc += h1cat[b * 100 + k] * fcw[k];
        out[b] = acc;
    }
}

extern "C" void kernel_launch(void* const* d_in, const int* in_sizes, int n_in,
                              void* d_out, int out_size, void* d_ws, size_t ws_size,
                              hipStream_t stream) {
    const float* x        = (const float*)d_in[0];
    const float* Wih_l0f  = (const float*)d_in[1];
    const float* Whh_l0f  = (const float*)d_in[2];
    const float* bih_l0f  = (const float*)d_in[3];
    const float* bhh_l0f  = (const float*)d_in[4];
    const float* Wih_l0b  = (const float*)d_in[5];
    const float* Whh_l0b  = (const float*)d_in[6];
    const float* bih_l0b  = (const float*)d_in[7];
    const float* bhh_l0b  = (const float*)d_in[8];
    const float* Wih_l1f  = (const float*)d_in[9];
    const float* Whh_l1f  = (const float*)d_in[10];
    const float* bih_l1f  = (const float*)d_in[11];
    const float* bhh_l1f  = (const float*)d_in[12];
    const float* Wih_l1b  = (const float*)d_in[13];
    /* Whh_l1b (d_in[14]) unused: h0=0 for the single backward step */
    const float* bih_l1b  = (const float*)d_in[15];
    const float* bhh_l1b  = (const float*)d_in[16];
    const float* fc_w     = (const float*)d_in[17];
    const float* fc_b     = (const float*)d_in[18];

    float* hl0   = (float*)d_ws;                                   // B*T*100 f32 = 209.7 MB
    float* h1cat = hl0 + (size_t)BATCH * TT * 100;                 // B*100
    float* stC   = h1cat + (size_t)BATCH * 100;                    // 1024*64
    float* stH   = stC + 1024 * 64;
    float* xpb   = stH + 1024 * 64;
    const size_t fixed_bytes = (size_t)((char*)xpb - (char*)d_ws);

    int CH = 16;
    for (int cand = 1024; cand >= 16; cand >>= 1) {
        if (fixed_bytes + (size_t)2 * BATCH * cand * GG * 4 <= ws_size) { CH = cand; break; }
    }
    const int nch = TT / CH;

    for (int ci = 0; ci < nch; ++ci) {
        const int t0 = ci * CH;
        xp_gemm<64, 2, false><<<dim3(128, 2), dim3(256), 0, stream>>>(
            x, Wih_l0f, bih_l0f, bhh_l0f, Wih_l0b, bih_l0b, bhh_l0b, xpb, t0, CH);
        lstm_scan<true><<<dim3(1024), dim3(64), 0, stream>>>(
            xpb, Whh_l0f, Whh_l0b, hl0, nullptr, stC, stH, t0, CH);
    }
    for (int ci = 0; ci < nch; ++ci) {
        const int t0 = ci * CH;
        xp_gemm<100, 4, true><<<dim3(256, 1), dim3(256), 0, stream>>>(
            hl0, Wih_l1f, bih_l1f, bhh_l1f, Wih_l1f, bih_l1f, bhh_l1f, xpb, t0, CH);
        lstm_scan<false><<<dim3(512), dim3(64), 0, stream>>>(
            xpb, Whh_l1f, Whh_l1f, nullptr, h1cat, stC, stH, t0, CH);
    }
    l1b_step<<<dim3(BATCH), dim3(256), 0, stream>>>(hl0, Wih_l1b, bih_l1b, bhh_l1b, h1cat);
    fc_out<<<dim3(2), dim3(256), 0, stream>>>(h1cat, fc_w, fc_b, (float*)d_out);
}

// Round 22
// 1591.350 us; speedup vs baseline: 1.0274x; 1.0274x over previous
//
#include <hip/hip_runtime.h>

// BiLSTM B=512 T=1024 D=64 H=50, 2 layers bidir, FC on h[:,-1].
//  Phase A (per T-chunk): xp_gemm l0 (MFMA split-bf16, both dirs) -> lstm_scan l0
//  Phase B (per T-chunk): xp_gemm l1f -> lstm_scan l1f (final h only)
//  Phase C: l1 backward single step at t=T-1 (h0=c0=0 -> no Whh), Phase D: FC.
//
// Round 22: EXACT round-17 build (best passing: 1593 us). Rounds 19-21 all
// core-dumped on structural variants of the scan (duo grids, waves_per_eu(2),
// dual px rings) -- the crash tracks regalloc/code-object corners around the
// asm-pin + asm-ring machinery, not any single attribute. Re-establishing the
// proven envelope: k-packed pk_fma (100/step), batched readlanes, depth-4 asm
// px ring with vmcnt(12), 100v+100a weight pins, waves_per_eu(1,1).

#define BATCH 512
#define TT    1024
#define HH    50
#define GG    200

typedef __attribute__((ext_vector_type(2))) float  f32x2;
typedef __attribute__((ext_vector_type(4))) float  f32x4;
typedef __attribute__((ext_vector_type(8))) short  bf16x8;

__device__ __forceinline__ float sigf(float x)     { return 1.f / (1.f + __expf(-x)); }
__device__ __forceinline__ float tanhfast(float x) { return 1.f - 2.f / (__expf(2.f * x) + 1.f); }

__device__ __forceinline__ void split8(const float (&v)[8], bf16x8& hi, bf16x8& lo) {
#pragma unroll
  for (int j = 0; j < 8; ++j) {
    unsigned b = __float_as_uint(v[j]);
    hi[j] = (short)(b >> 16);
    float rem = v[j] - __uint_as_float(b & 0xFFFF0000u);
    lo[j] = (short)(__float_as_uint(rem) >> 16);
  }
}

// B-frag: B[k][col], k = ks*32 + 8*(lane>>4) + j, col = n*16 + (lane&15)
__device__ __forceinline__ void load_wfrag(const float* __restrict__ W, int ld, int kvalid,
                                           int n, int ks, int lane, bf16x8& hi, bf16x8& lo) {
  const int col = n * 16 + (lane & 15);
  const int kb  = ks * 32 + ((lane >> 4) << 3);
  float v[8];
#pragma unroll
  for (int j = 0; j < 8; ++j) {
    const int k = kb + j;
    v[j] = (col < GG && k < kvalid) ? W[col * ld + k] : 0.f;
  }
  split8(v, hi, lo);
}

// ================= xp GEMM: XP[dir][b][s][200] = X[row(b,s)] @ W^T + bih + bhh =================
template<int DINK, int KS, bool SPLITN>
__global__ __launch_bounds__(256, 1) void xp_gemm(
    const float* __restrict__ X,
    const float* __restrict__ Wf, const float* __restrict__ bihf, const float* __restrict__ bhhf,
    const float* __restrict__ Wb, const float* __restrict__ bihb, const float* __restrict__ bhhb,
    float* __restrict__ XP, int t0, int CH)
{
  const int lane = threadIdx.x & 63;
  const int wid  = threadIdx.x >> 6;
  const int dir  = blockIdx.y;
  const float* W   = dir ? Wb : Wf;
  const float* bih = dir ? bihb : bihf;
  const float* bhh = dir ? bhhb : bhhf;

  constexpr int MAXT = SPLITN ? 7 : 13;
  const int tb = SPLITN ? ((wid & 1) * 7) : 0;
  const int tn = SPLITN ? ((wid & 1) ? 6 : 7) : 13;

  bf16x8 whi[MAXT][KS], wlo[MAXT][KS];
  float bias[MAXT];
#pragma unroll
  for (int i = 0; i < MAXT; ++i) {
    if (i < tn) {
      const int n = tb + i;
#pragma unroll
      for (int ks = 0; ks < KS; ++ks)
        load_wfrag(W, DINK, DINK, n, ks, lane, whi[i][ks], wlo[i][ks]);
      const int col = n * 16 + (lane & 15);
      bias[i] = (col < GG) ? (bih[col] + bhh[col]) : 0.f;
    }
  }

  const int rw      = SPLITN ? ((int)blockIdx.x * 2 + (wid >> 1)) : ((int)blockIdx.x * 4 + wid);
  const int stride  = SPLITN ? ((int)gridDim.x * 2) : ((int)gridDim.x * 4);
  const int gpb     = CH >> 4;
  const int ngroups = BATCH * gpb;
  const int m = lane & 15;

  auto loadA = [&](int g, float (&v)[KS][8]) {
    const int b    = g / gpb;
    const int toff = (g - b * gpb) << 4;
    const int s    = toff + m;
    const int tg   = dir ? (TT - 1 - (t0 + s)) : (t0 + s);
    const float* base = X + ((size_t)b * TT + tg) * DINK;
#pragma unroll
    for (int ks = 0; ks < KS; ++ks) {
      const int kb = ks * 32 + ((lane >> 4) << 3);
      if (kb + 8 <= DINK) {
        f32x4 a = *(const f32x4*)(base + kb);
        f32x4 bq = *(const f32x4*)(base + kb + 4);
#pragma unroll
        for (int q = 0; q < 4; ++q) { v[ks][q] = a[q]; v[ks][4 + q] = bq[q]; }
      } else if (kb < DINK) {
        f32x4 a = *(const f32x4*)(base + kb);
#pragma unroll
        for (int q = 0; q < 4; ++q) { v[ks][q] = a[q]; v[ks][4 + q] = 0.f; }
      } else {
#pragma unroll
        for (int q = 0; q < 8; ++q) v[ks][q] = 0.f;
      }
    }
  };

  float vc[KS][8], vn[KS][8];
  if (rw < ngroups) loadA(rw, vc);
  for (int g = rw; g < ngroups; g += stride) {
    if (g + stride < ngroups) loadA(g + stride, vn);
    bf16x8 ah[KS], al[KS];
#pragma unroll
    for (int ks = 0; ks < KS; ++ks) split8(vc[ks], ah[ks], al[ks]);
    const int b    = g / gpb;
    const int toff = (g - b * gpb) << 4;
    float* out = XP + (((size_t)dir * BATCH + b) * CH + toff) * GG;
#pragma unroll
    for (int i = 0; i < MAXT; ++i) {
      if (i < tn) {
        f32x4 acc = {0.f, 0.f, 0.f, 0.f};
#pragma unroll
        for (int ks = 0; ks < KS; ++ks) {
          acc = __builtin_amdgcn_mfma_f32_16x16x32_bf16(ah[ks], whi[i][ks], acc, 0, 0, 0);
          acc = __builtin_amdgcn_mfma_f32_16x16x32_bf16(al[ks], whi[i][ks], acc, 0, 0, 0);
          acc = __builtin_amdgcn_mfma_f32_16x16x32_bf16(ah[ks], wlo[i][ks], acc, 0, 0, 0);
        }
        const int col = (tb + i) * 16 + (lane & 15);
        if (col < GG) {
          const int rb = (lane >> 4) * 4;
#pragma unroll
          for (int q = 0; q < 4; ++q) out[(size_t)(rb + q) * GG + col] = acc[q] + bias[i];
        }
      }
    }
#pragma unroll
    for (int ks = 0; ks < KS; ++ks)
#pragma unroll
      for (int q = 0; q < 8; ++q) vc[ks][q] = vn[ks][q];
  }
}

// ================= scan: one WAVE per (dir,seq); no barriers, no LDS ===========
// K-packed fp32: 4 pair-accumulators, 25 pk_fma per gate, hp = natural hk pairs.
template<bool L0>
__global__ __attribute__((amdgpu_flat_work_group_size(64, 64), amdgpu_waves_per_eu(1, 1)))
void lstm_scan(
    const float* __restrict__ XP,     // [dir][b][s][200], bias included
    const float* __restrict__ Whh_f, const float* __restrict__ Whh_b,
    float* __restrict__ hseq,         // L0: [b][t][100]
    float* __restrict__ hlast,        // !L0: [b][100] cols 0..49
    float* __restrict__ stC, float* __restrict__ stH,
    int t0, int CH)
{
  const int lane = threadIdx.x;                  // 0..63
  const int unit = blockIdx.x;                   // (dir*512+b) for L0, b for L1
  const int dir  = L0 ? (unit >> 9) : 0;
  const int b    = L0 ? (unit & 511) : unit;
  const bool act = lane < HH;
  const int  jw  = act ? lane : 0;               // clamped: safe loads for dead lanes
  const float* Whh = (L0 && dir) ? Whh_b : Whh_f;

  // ---- weights as k-pairs: wI2,wF2 -> VGPR; wG2,wO2 -> AGPR (classes
  // proven perf-equal on the unified file, r15).
  f32x2 wI2[25], wF2[25], wG2[25], wO2[25];
#pragma unroll
  for (int m = 0; m < 25; ++m) {
    wI2[m].x = Whh[(size_t)jw * HH + 2 * m];
    wI2[m].y = Whh[(size_t)jw * HH + 2 * m + 1];
    wF2[m].x = Whh[(size_t)(HH + jw) * HH + 2 * m];
    wF2[m].y = Whh[(size_t)(HH + jw) * HH + 2 * m + 1];
    wG2[m].x = Whh[(size_t)(2 * HH + jw) * HH + 2 * m];
    wG2[m].y = Whh[(size_t)(2 * HH + jw) * HH + 2 * m + 1];
    wO2[m].x = Whh[(size_t)(3 * HH + jw) * HH + 2 * m];
    wO2[m].y = Whh[(size_t)(3 * HH + jw) * HH + 2 * m + 1];
  }
#pragma unroll
  for (int m = 0; m < 25; ++m) {
    asm volatile("" : "+v"(wI2[m]), "+v"(wF2[m]), "+a"(wG2[m]), "+a"(wO2[m]));
  }

  float c = 0.f, h = 0.f;
  if (t0 > 0 && act) { c = stC[unit * 64 + lane]; h = stH[unit * 64 + lane]; }

  const float* xp = XP + (size_t)unit * CH * GG + jw;   // lane-adjusted base

  // ---- depth-4 asm load ring (round 11, verified) ----
  float px[4][4];
#pragma unroll
  for (int d = 0; d < 4; ++d) {
    const float* pa = xp + (size_t)d * GG;
    asm volatile("global_load_dword %0, %1, off"             : "=v"(px[d][0]) : "v"(pa));
    asm volatile("global_load_dword %0, %1, off offset:200"  : "=v"(px[d][1]) : "v"(pa));
    asm volatile("global_load_dword %0, %1, off offset:400"  : "=v"(px[d][2]) : "v"(pa));
    asm volatile("global_load_dword %0, %1, off offset:600"  : "=v"(px[d][3]) : "v"(pa));
  }

  for (int s0 = 0; s0 < CH; s0 += 4) {
#pragma unroll
    for (int d = 0; d < 4; ++d) {
      const int s = s0 + d;

      // ---- batched broadcast: all 50 readlanes first (hazards amortize) ----
      float hk[HH];
#pragma unroll
      for (int k = 0; k < HH; ++k)
        hk[k] = __uint_as_float((unsigned)__builtin_amdgcn_readlane((int)__float_as_uint(h), k));
      __builtin_amdgcn_sched_barrier(0);   // keep the batch ahead of the FMAs

      asm volatile("s_waitcnt vmcnt(12)"); // px(s) ready (12 newer loads in flight)
      __builtin_amdgcn_sched_barrier(0);   // rule #18: nothing crosses the wait

      f32x2 aI2, aF2, aG2, aO2;
      aI2.x = px[d][0]; aI2.y = 0.f;
      aF2.x = px[d][1]; aF2.y = 0.f;
      aG2.x = px[d][2]; aG2.y = 0.f;
      aO2.x = px[d][3]; aO2.y = 0.f;
#pragma unroll
      for (int m = 0; m < 25; ++m) {
        f32x2 hp; hp.x = hk[2 * m]; hp.y = hk[2 * m + 1];
        aI2 = hp * wI2[m] + aI2;     // contraction -> v_pk_fma_f32
        aF2 = hp * wF2[m] + aF2;
        aG2 = hp * wG2[m] + aG2;
        aO2 = hp * wO2[m] + aO2;
      }
      const float aI = aI2.x + aI2.y;
      const float aF = aF2.x + aF2.y;
      const float aG = aG2.x + aG2.y;
      const float aO = aO2.x + aO2.y;

      // refill slot d for step s+4 (after consumption; WAR on px[d] in-order)
      {
        int sp = s + 4; if (sp > CH - 1) sp = CH - 1;
        const float* pa = xp + (size_t)sp * GG;
        asm volatile("global_load_dword %0, %1, off"             : "=v"(px[d][0]) : "v"(pa));
        asm volatile("global_load_dword %0, %1, off offset:200"  : "=v"(px[d][1]) : "v"(pa));
        asm volatile("global_load_dword %0, %1, off offset:400"  : "=v"(px[d][2]) : "v"(pa));
        asm volatile("global_load_dword %0, %1, off offset:600"  : "=v"(px[d][3]) : "v"(pa));
      }

      const float iv = sigf(aI), fv = sigf(aF), gv = tanhfast(aG), ov = sigf(aO);
      c = fv * c + iv * gv;
      h = ov * tanhfast(c);
      if (act) {
        if (L0) {
          const int tg = dir ? (TT - 1 - (t0 + s)) : (t0 + s);
          hseq[((size_t)b * TT + tg) * 100 + dir * HH + lane] = h;
        } else if (t0 + s == TT - 1) {
          hlast[b * 100 + lane] = h;
        }
      }
    }
  }
  if (act) { stC[unit * 64 + lane] = c; stH[unit * 64 + lane] = h; }
}

// ------------- Layer 1 backward at t=T-1: single step, h0=c0=0 -> no Whh term. ----
__global__ __launch_bounds__(256) void l1b_step(
    const float* __restrict__ hl0, const float* __restrict__ Wih,
    const float* __restrict__ bih, const float* __restrict__ bhh,
    float* __restrict__ h1cat)
{
    const int row = blockIdx.x;
    const int tid = threadIdx.x;
    __shared__ float in_s[100];
    __shared__ float gbuf[4 * HH];

    const float* inp = hl0 + ((size_t)row * TT + (TT - 1)) * 100;
    if (tid < 100) in_s[tid] = inp[tid];
    __syncthreads();
    if (tid < 4 * HH) {
        float acc = bih[tid] + bhh[tid];
#pragma unroll
        for (int k = 0; k < 100; ++k) acc += in_s[k] * Wih[tid * 100 + k];
        gbuf[tid] = acc;
    }
    __syncthreads();
    if (tid < HH) {
        float iv = sigf(gbuf[tid]);
        float gv = tanhfast(gbuf[2 * HH + tid]);
        float ov = sigf(gbuf[3 * HH + tid]);
        float cc = iv * gv;
        h1cat[row * 100 + HH + tid] = ov * tanhfast(cc);
    }
}

__global__ void fc_out(const float* __restrict__ h1cat,
                       const float* __restrict__ fcw, const float* __restrict__ fcb,
                       float* __restrict__ out)
{
    const int b = blockIdx.x * blockDim.x + threadIdx.x;
    if (b < BATCH) {
        float acc = fcb[0];
#pragma unroll 4
        for (int k = 0; k < 100; ++k) acc += h1cat[b * 100 + k] * fcw[k];
        out[b] = acc;
    }
}

extern "C" void kernel_launch(void* const* d_in, const int* in_sizes, int n_in,
                              void* d_out, int out_size, void* d_ws, size_t ws_size,
                              hipStream_t stream) {
    const float* x        = (const float*)d_in[0];
    const float* Wih_l0f  = (const float*)d_in[1];
    const float* Whh_l0f  = (const float*)d_in[2];
    const float* bih_l0f  = (const float*)d_in[3];
    const float* bhh_l0f  = (const float*)d_in[4];
    const float* Wih_l0b  = (const float*)d_in[5];
    const float* Whh_l0b  = (const float*)d_in[6];
    const float* bih_l0b  = (const float*)d_in[7];
    const float* bhh_l0b  = (const float*)d_in[8];
    const float* Wih_l1f  = (const float*)d_in[9];
    const float* Whh_l1f  = (const float*)d_in[10];
    const float* bih_l1f  = (const float*)d_in[11];
    const float* bhh_l1f  = (const float*)d_in[12];
    const float* Wih_l1b  = (const float*)d_in[13];
    /* Whh_l1b (d_in[14]) unused: h0=0 for the single backward step */
    const float* bih_l1b  = (const float*)d_in[15];
    const float* bhh_l1b  = (const float*)d_in[16];
    const float* fc_w     = (const float*)d_in[17];
    const float* fc_b     = (const float*)d_in[18];

    float* hl0   = (float*)d_ws;                                   // B*T*100 f32 = 209.7 MB
    float* h1cat = hl0 + (size_t)BATCH * TT * 100;                 // B*100
    float* stC   = h1cat + (size_t)BATCH * 100;                    // 1024*64
    float* stH   = stC + 1024 * 64;
    float* xpb   = stH + 1024 * 64;
    const size_t fixed_bytes = (size_t)((char*)xpb - (char*)d_ws);

    int CH = 16;
    for (int cand = 1024; cand >= 16; cand >>= 1) {
        if (fixed_bytes + (size_t)2 * BATCH * cand * GG * 4 <= ws_size) { CH = cand; break; }
    }
    const int nch = TT / CH;

    for (int ci = 0; ci < nch; ++ci) {
        const int t0 = ci * CH;
        xp_gemm<64, 2, false><<<dim3(128, 2), dim3(256), 0, stream>>>(
            x, Wih_l0f, bih_l0f, bhh_l0f, Wih_l0b, bih_l0b, bhh_l0b, xpb, t0, CH);
        lstm_scan<true><<<dim3(1024), dim3(64), 0, stream>>>(
            xpb, Whh_l0f, Whh_l0b, hl0, nullptr, stC, stH, t0, CH);
    }
    for (int ci = 0; ci < nch; ++ci) {
        const int t0 = ci * CH;
        xp_gemm<100, 4, true><<<dim3(256, 1), dim3(256), 0, stream>>>(
            hl0, Wih_l1f, bih_l1f, bhh_l1f, Wih_l1f, bih_l1f, bhh_l1f, xpb, t0, CH);
        lstm_scan<false><<<dim3(512), dim3(64), 0, stream>>>(
            xpb, Whh_l1f, Whh_l1f, nullptr, h1cat, stC, stH, t0, CH);
    }
    l1b_step<<<dim3(BATCH), dim3(256), 0, stream>>>(hl0, Wih_l1b, bih_l1b, bhh_l1b, h1cat);
    fc_out<<<dim3(2), dim3(256), 0, stream>>>(h1cat, fc_w, fc_b, (float*)d_out);
}